// Round 1
// 2803.819 us; speedup vs baseline: 3.7815x; 3.7815x over previous
//
#include <hip/hip_runtime.h>
#include <hip/hip_fp16.h>

// ============================================================================
// GRU scan, T=256, cells=B*A=512, H=512.
//   x_gates = ins @ Wi + bi  (fused, per step)
//   hg      = h   @ Wh
//   r=sig(xr+hr), z=sig(xz+hz), n=tanh(xn + r*(hn+bhn))
//   new_h=(1-z)n+z*h ; carry = reset ? 0 : new_h ; ys[t]=new_h
//
// Decomposition: 16 independent "mg" pipelines of 32 cells each. Each pipeline
// = 16 workgroups (ng = 32-column slice of H), per-step sync via a 16-wg
// atomic generation barrier (no grid-wide barrier).
//
// R1 change: NO __threadfence(). On gfx950 an agent-scope fence lowers to
// buffer_wbl2 (release) / buffer_inv (acquire) — full per-XCD L2
// writeback/invalidate, twice per step per workgroup. Counter evidence:
// WRITE_SIZE showed the entire h ping-pong (134 MB) forced to memory.
// Instead, all cross-wg data (h ping-pong, counters) uses relaxed
// AGENT-scope atomics, which the compiler emits with sc0 sc1 (bypass
// L1/L2, served at MALL = the XCD-coherent point). Ordering: syncthreads
// drains vmcnt(0) before s_barrier; explicit waitcnt before counter add.
// Wave 0 carries its own h slice in registers (hprev) — a plain re-read
// would be L1-stale without the acquire fence.
//
// Per wg: 4 waves = 4 k-quarters (K=128 each). Weights (6 streams: Wi/Wh x
// r/z/n, f16) live in 192 VGPRs/lane for the whole kernel. A-fragments load
// direct global->VGPR in MFMA A-layout. LDS only for 4-way k-reduction.
// mfma_f32_32x32x16_f16: A lane l: m=l&31, k=8*(l>>5)+j ; B: n=l&31, same k ;
// C: col=l&31, row=(reg&3)+8*(reg>>2)+4*(l>>5).
// ============================================================================

#define T_STEPS 256
#define NCELL   512
#define HD      512
#define G3      1536

typedef _Float16 f16;
typedef _Float16 half8   __attribute__((ext_vector_type(8)));
typedef float    floatx16 __attribute__((ext_vector_type(16)));
typedef float    float4v  __attribute__((ext_vector_type(4)));
typedef unsigned long long u64;

// ws layout (bytes):
//   [0, 3145728)            weight packs f16: [ng(16)][s(6)][it(32)][lane(64)][j(8)]
//   [3145728, 4194304)      h ping-pong: 2 x 512x512 f16
//   [4194304, 4198400)      barrier counters (16, stride 128B)
#define PACKS_ELEMS (16 * 6 * 32 * 64 * 8)
#define HBUF_OFF    (PACKS_ELEMS * 2)
#define HBUF_ELEMS  (NCELL * HD)
#define CNT_OFF     (HBUF_OFF + 2 * HBUF_ELEMS * 2)

__global__ void pack_weights(const float* __restrict__ Wi,
                             const float* __restrict__ Wh,
                             f16* __restrict__ packs) {
    int idx = blockIdx.x * blockDim.x + threadIdx.x;
    if (idx >= PACKS_ELEMS) return;
    int j  = idx & 7;
    int l  = (idx >> 3) & 63;
    int it = (idx >> 9) & 31;
    int s  = (idx >> 14) % 6;
    int ng = idx / (6 << 14);
    int k    = it * 16 + (l >> 5) * 8 + j;                 // MFMA B k-index
    int gcol = (s % 3) * 512 + ng * 32 + (l & 31);         // gate column
    const float* W = (s < 3) ? Wi : Wh;
    packs[idx] = (f16)W[(size_t)k * G3 + gcol];
}

__launch_bounds__(256, 1)
__global__ void gru_scan(const float* __restrict__ ins,
                         const int*   __restrict__ resets,
                         const float* __restrict__ bi,
                         const float* __restrict__ bhn,
                         const f16*   __restrict__ packs,
                         f16*         __restrict__ hbuf,
                         int*         __restrict__ cnt,
                         float*       __restrict__ out) {
    __shared__ float red[3][4][4][64][4];   // 48 KB: [wave-1][acc][quad][lane][4]

    const int bid  = blockIdx.x;
    const int xcd  = bid & 7;
    const int rest = bid >> 3;
    const int ng   = rest & 15;             // 32-column slice of H
    const int mg   = xcd + 8 * (rest >> 4); // 32-cell pipeline id (XCD-local)
    const int tid  = threadIdx.x;
    const int lane = tid & 63;
    const int w    = tid >> 6;              // wave = k-quarter
    const int lm   = lane & 31;
    const int lh   = lane >> 5;

    // ---- persistent B fragments: 6 streams x 8 k-iters, 192 VGPRs/lane ----
    half8 bw[6][8];
    {
        const half8* p = (const half8*)packs;
#pragma unroll
        for (int s = 0; s < 6; ++s)
#pragma unroll
            for (int itl = 0; itl < 8; ++itl)
                bw[s][itl] = p[((ng * 6 + s) * 32 + (w * 8 + itl)) * 64 + lane];
    }

    // biases for wave-0 elementwise (static, keep in regs)
    const int col0 = ng * 32 + lm;
    const float bir = bi[col0], biz = bi[512 + col0], bin = bi[1024 + col0];
    const float bhv = bhn[col0];

    const int cell_a = mg * 32 + lm;          // A-fragment row (cell)
    const int kbase  = w * 128 + lh * 8;      // A-fragment k base for this lane
    const f16* hb0 = hbuf;
    const f16* hb1 = hbuf + HBUF_ELEMS;

    // wave-0 register carry of this wg's own [32x32] h slice (post-reset).
    // h0 = 0. Indexed only by compile-time-unrolled e (stays in VGPRs).
    float hprev[16];
#pragma unroll
    for (int e = 0; e < 16; ++e) hprev[e] = 0.f;

    // ---- prefetch x(t=0) fp32, convert to f16 fragments ----
    float4v xa[8], xb[8];
    {
        const float* xr0 = ins + (size_t)cell_a * HD + kbase;
#pragma unroll
        for (int itl = 0; itl < 8; ++itl) {
            const float4v* px = (const float4v*)(xr0 + itl * 16);
            xa[itl] = px[0];
            xb[itl] = px[1];
        }
    }
    half8 xf[8];
#pragma unroll
    for (int itl = 0; itl < 8; ++itl) {
        half8 v;
#pragma unroll
        for (int e = 0; e < 4; ++e) { v[e] = (f16)xa[itl][e]; v[4 + e] = (f16)xb[itl][e]; }
        xf[itl] = v;
    }

    for (int t = 0; t < T_STEPS; ++t) {
        const f16* hr_ = (t & 1) ? hb1 : hb0;
        f16*       hw_ = (f16*)((t & 1) ? hb0 : hb1);

        // h fragments for this step (critical path: issue first).
        // Relaxed agent atomics -> sc0 sc1 -> served at MALL (coherent
        // across CUs/XCDs), no cache-maintenance fences needed.
        half8 hf[8];
        {
            const u64* hsrc = (const u64*)(hr_ + (size_t)cell_a * HD + kbase);
#pragma unroll
            for (int itl = 0; itl < 8; ++itl) {
                union { u64 q[2]; half8 v; } u;
                u.q[0] = __hip_atomic_load(hsrc + itl * 4 + 0, __ATOMIC_RELAXED,
                                           __HIP_MEMORY_SCOPE_AGENT);
                u.q[1] = __hip_atomic_load(hsrc + itl * 4 + 1, __ATOMIC_RELAXED,
                                           __HIP_MEMORY_SCOPE_AGENT);
                hf[itl] = u.v;
            }
        }

        // prefetch x(t+1) fp32 (independent of h; hides HBM latency)
        {
            int tn = (t + 1 < T_STEPS) ? (t + 1) : t;
            const float* xrn = ins + ((size_t)tn * NCELL + cell_a) * HD + kbase;
#pragma unroll
            for (int itl = 0; itl < 8; ++itl) {
                const float4v* px = (const float4v*)(xrn + itl * 16);
                xa[itl] = px[0];
                xb[itl] = px[1];
            }
        }

        // ---- MFMA: 6 streams x 8 iters over this wave's k-quarter ----
        floatx16 ar, az, anx, anh;
#pragma unroll
        for (int i = 0; i < 16; ++i) { ar[i] = 0.f; az[i] = 0.f; anx[i] = 0.f; anh[i] = 0.f; }
#pragma unroll
        for (int itl = 0; itl < 8; ++itl) {
            ar  = __builtin_amdgcn_mfma_f32_32x32x16_f16(xf[itl], bw[0][itl], ar,  0, 0, 0);
            az  = __builtin_amdgcn_mfma_f32_32x32x16_f16(xf[itl], bw[1][itl], az,  0, 0, 0);
            anx = __builtin_amdgcn_mfma_f32_32x32x16_f16(xf[itl], bw[2][itl], anx, 0, 0, 0);
            ar  = __builtin_amdgcn_mfma_f32_32x32x16_f16(hf[itl], bw[3][itl], ar,  0, 0, 0);
            az  = __builtin_amdgcn_mfma_f32_32x32x16_f16(hf[itl], bw[4][itl], az,  0, 0, 0);
            anh = __builtin_amdgcn_mfma_f32_32x32x16_f16(hf[itl], bw[5][itl], anh, 0, 0, 0);
        }

        // convert x(t+1) to f16 frags (after last use of xf this step)
#pragma unroll
        for (int itl = 0; itl < 8; ++itl) {
            half8 v;
#pragma unroll
            for (int e = 0; e < 4; ++e) { v[e] = (f16)xa[itl][e]; v[4 + e] = (f16)xb[itl][e]; }
            xf[itl] = v;
        }

        // ---- k-reduction: waves 1..3 dump partials, wave 0 sums ----
        if (w != 0) {
#pragma unroll
            for (int q = 0; q < 4; ++q) {
                float4v v;
                v[0] = ar[4*q]; v[1] = ar[4*q+1]; v[2] = ar[4*q+2]; v[3] = ar[4*q+3];
                *(float4v*)&red[w - 1][0][q][lane][0] = v;
                v[0] = az[4*q]; v[1] = az[4*q+1]; v[2] = az[4*q+2]; v[3] = az[4*q+3];
                *(float4v*)&red[w - 1][1][q][lane][0] = v;
                v[0] = anx[4*q]; v[1] = anx[4*q+1]; v[2] = anx[4*q+2]; v[3] = anx[4*q+3];
                *(float4v*)&red[w - 1][2][q][lane][0] = v;
                v[0] = anh[4*q]; v[1] = anh[4*q+1]; v[2] = anh[4*q+2]; v[3] = anh[4*q+3];
                *(float4v*)&red[w - 1][3][q][lane][0] = v;
            }
        }
        __syncthreads();

        if (w == 0) {
#pragma unroll
            for (int ww = 0; ww < 3; ++ww) {
#pragma unroll
                for (int q = 0; q < 4; ++q) {
                    float4v v0 = *(const float4v*)&red[ww][0][q][lane][0];
                    float4v v1 = *(const float4v*)&red[ww][1][q][lane][0];
                    float4v v2 = *(const float4v*)&red[ww][2][q][lane][0];
                    float4v v3 = *(const float4v*)&red[ww][3][q][lane][0];
#pragma unroll
                    for (int e = 0; e < 4; ++e) {
                        ar[4*q+e]  += v0[e];
                        az[4*q+e]  += v1[e];
                        anx[4*q+e] += v2[e];
                        anh[4*q+e] += v3[e];
                    }
                }
            }
            // ---- elementwise GRU update for [32 cells x 32 cols] ----
#pragma unroll
            for (int e = 0; e < 16; ++e) {
                int row  = (e & 3) + 8 * (e >> 2) + 4 * lh;
                int cell = mg * 32 + row;
                float var = ar[e]  + bir;
                float vaz = az[e]  + biz;
                float vnx = anx[e] + bin;
                float vnh = anh[e] + bhv;
                float r = 1.0f / (1.0f + __expf(-var));
                float z = 1.0f / (1.0f + __expf(-vaz));
                float hp = hprev[e];                      // register carry
                float narg = vnx + r * vnh;
                narg = fminf(fmaxf(narg, -30.f), 30.f);  // avoid inf/inf in tanh
                float ex = __expf(2.f * narg);
                float n  = (ex - 1.f) / (ex + 1.f);
                float nh = (1.f - z) * n + z * hp;
                out[((size_t)t * NCELL + cell) * HD + col0] = nh;   // pre-reset output
                int rs = resets[t * NCELL + cell];
                float carry = rs ? 0.f : nh;
                hprev[e] = carry;
                union { unsigned short s; f16 h; } cv; cv.h = (f16)carry;
                __hip_atomic_store((unsigned short*)&hw_[(size_t)cell * HD + col0],
                                   cv.s, __ATOMIC_RELAXED, __HIP_MEMORY_SCOPE_AGENT);
            }
        }

        // ---- 16-wg pipeline barrier (generation count) ----
        // syncthreads drains vmcnt(0) per wave (wave0's sc0sc1 h-stores have
        // reached the coherence point before tid0's counter bump below).
        __syncthreads();
        if (tid == 0) {
            asm volatile("s_waitcnt vmcnt(0)" ::: "memory");  // belt & braces
            atomicAdd(&cnt[mg * 32], 1);
            int target = 16 * (t + 1);
            while (__hip_atomic_load(&cnt[mg * 32], __ATOMIC_RELAXED,
                                     __HIP_MEMORY_SCOPE_AGENT) < target) { }
        }
        __syncthreads();
        // no acquire fence: next-step h reads are sc0sc1 atomics (L1/L2 bypass)
    }
}

extern "C" void kernel_launch(void* const* d_in, const int* in_sizes, int n_in,
                              void* d_out, int out_size, void* d_ws, size_t ws_size,
                              hipStream_t stream) {
    const float* ins    = (const float*)d_in[0];
    const int*   resets = (const int*)  d_in[1];
    const float* Wi     = (const float*)d_in[2];
    const float* bi     = (const float*)d_in[3];
    const float* Wh     = (const float*)d_in[4];
    const float* bhn    = (const float*)d_in[5];
    float* out = (float*)d_out;

    char* ws = (char*)d_ws;
    f16* packs = (f16*)ws;
    f16* hbuf  = (f16*)(ws + HBUF_OFF);
    int* cnt   = (int*)(ws + CNT_OFF);

    // zero h ping-pong buffers + barrier counters (re-poisoned to 0xAA each call)
    hipMemsetAsync(ws + HBUF_OFF, 0, (size_t)2 * HBUF_ELEMS * 2 + 4096, stream);

    pack_weights<<<(PACKS_ELEMS + 255) / 256, 256, 0, stream>>>(Wi, Wh, packs);
    gru_scan<<<256, 256, 0, stream>>>(ins, resets, bi, bhn, packs, hbuf, cnt, out);
}

// Round 2
// 1990.314 us; speedup vs baseline: 5.3271x; 1.4087x over previous
//
#include <hip/hip_runtime.h>
#include <hip/hip_fp16.h>

// ============================================================================
// GRU scan, T=256, cells=B*A=512, H=512.
//   x_gates = ins @ Wi + bi  (fused, per step)
//   hg      = h   @ Wh
//   r=sig(xr+hr), z=sig(xz+hz), n=tanh(xn + r*(hn+bhn))
//   new_h=(1-z)n+z*h ; carry = reset ? 0 : new_h ; ys[t]=new_h
//
// Decomposition: 16 independent "mg" pipelines of 32 cells each. Each pipeline
// = 16 workgroups (ng = 32-column slice of H). All cross-wg data (h ping-pong,
// flags) uses relaxed AGENT-scope atomics (sc0 sc1 -> MALL, the cross-XCD
// coherence point) -- NO __threadfence (R1: fences lowered to buffer_wbl2/
// buffer_inv = full L2 writeback/inv per step, 4x slowdown).
//
// R2 changes (attack the ~24k-cycle serial step latency):
//  * Flag barrier instead of atomicAdd generation counter: producer does
//    h-stores -> __syncthreads (compiler drains vmcnt(0) before s_barrier)
//    -> tid0 stores flag[mg][ng]=t+1 (plain relaxed store, no RMW
//    serialization). Consumers: ALL waves poll the 16-flag line directly
//    (lane&15-indexed load + __any) and proceed straight to their h-loads --
//    removes the atomicAdd round-trip AND the trailing __syncthreads.
//    Ordering: flag observed==t+1 => producer's h-stores were drained
//    (vmcnt 0) before flag store issued => visible at MALL before flag.
//  * Tail parallelized across all 4 waves: every wave dumps all 4 acc quads
//    to LDS; wave w re-reads quad w of all 4 waves (own quad via LDS too --
//    keeps all ext_vector indices compile-time, avoids scratch), reduces,
//    does elementwise for its 8 rows, stores its h slice. hprev carry is
//    per-wave float[4].
//  * x-side work (x-MFMAs for step t, global prefetch of x(t+1)) moved
//    BEFORE the poll -- executes inside the barrier-wait window.
//
// Per wg: 4 waves = 4 k-quarters (K=128 each). Weights (6 streams: Wi/Wh x
// r/z/n, f16) live in 192 VGPRs/lane for the whole kernel. A-fragments load
// direct global->VGPR in MFMA A-layout. LDS only for 4-way k-reduction.
// mfma_f32_32x32x16_f16: A lane l: m=l&31, k=8*(l>>5)+j ; B: n=l&31, same k ;
// C: col=l&31, row=(reg&3)+8*(reg>>2)+4*(l>>5).
// ============================================================================

#define T_STEPS 256
#define NCELL   512
#define HD      512
#define G3      1536

typedef _Float16 f16;
typedef _Float16 half8   __attribute__((ext_vector_type(8)));
typedef float    floatx16 __attribute__((ext_vector_type(16)));
typedef float    float4v  __attribute__((ext_vector_type(4)));
typedef unsigned long long u64;

// ws layout (bytes):
//   [0, 3145728)            weight packs f16: [ng(16)][s(6)][it(32)][lane(64)][j(8)]
//   [3145728, 4194304)      h ping-pong: 2 x 512x512 f16
//   [4194304, ...)          flags: int[16 mg][32] (one 64B line per mg, 128B stride)
#define PACKS_ELEMS (16 * 6 * 32 * 64 * 8)
#define HBUF_OFF    (PACKS_ELEMS * 2)
#define HBUF_ELEMS  (NCELL * HD)
#define CNT_OFF     (HBUF_OFF + 2 * HBUF_ELEMS * 2)

__global__ void pack_weights(const float* __restrict__ Wi,
                             const float* __restrict__ Wh,
                             f16* __restrict__ packs) {
    int idx = blockIdx.x * blockDim.x + threadIdx.x;
    if (idx >= PACKS_ELEMS) return;
    int j  = idx & 7;
    int l  = (idx >> 3) & 63;
    int it = (idx >> 9) & 31;
    int s  = (idx >> 14) % 6;
    int ng = idx / (6 << 14);
    int k    = it * 16 + (l >> 5) * 8 + j;                 // MFMA B k-index
    int gcol = (s % 3) * 512 + ng * 32 + (l & 31);         // gate column
    const float* W = (s < 3) ? Wi : Wh;
    packs[idx] = (f16)W[(size_t)k * G3 + gcol];
}

__launch_bounds__(256, 1)
__global__ void gru_scan(const float* __restrict__ ins,
                         const int*   __restrict__ resets,
                         const float* __restrict__ bi,
                         const float* __restrict__ bhn,
                         const f16*   __restrict__ packs,
                         f16*         __restrict__ hbuf,
                         int*         __restrict__ flags,
                         float*       __restrict__ out) {
    __shared__ float red[4][4][4][64][4];   // 64 KB: [wave][acc][quad][lane][4]

    const int bid  = blockIdx.x;
    const int xcd  = bid & 7;
    const int rest = bid >> 3;
    const int ng   = rest & 15;             // 32-column slice of H
    const int mg   = xcd + 8 * (rest >> 4); // 32-cell pipeline id (XCD-local)
    const int tid  = threadIdx.x;
    const int lane = tid & 63;
    const int w    = tid >> 6;              // wave = k-quarter
    const int lm   = lane & 31;
    const int lh   = lane >> 5;

    // ---- persistent B fragments: 6 streams x 8 k-iters, 192 VGPRs/lane ----
    half8 bw[6][8];
    {
        const half8* p = (const half8*)packs;
#pragma unroll
        for (int s = 0; s < 6; ++s)
#pragma unroll
            for (int itl = 0; itl < 8; ++itl)
                bw[s][itl] = p[((ng * 6 + s) * 32 + (w * 8 + itl)) * 64 + lane];
    }

    // biases (all waves do elementwise now)
    const int col0 = ng * 32 + lm;
    const float bir = bi[col0], biz = bi[512 + col0], bin = bi[1024 + col0];
    const float bhv = bhn[col0];

    const int cell_a = mg * 32 + lm;          // A-fragment row (cell)
    const int kbase  = w * 128 + lh * 8;      // A-fragment k base for this lane
    const int row0   = 8 * w + 4 * lh;        // first output row of this wave's quad
    const f16* hb0 = hbuf;
    const f16* hb1 = hbuf + HBUF_ELEMS;
    int* myflags = flags + mg * 32;

    // per-wave register carry of h for this wave's 8 rows x 32 cols (quad w).
    float hprev[4];
#pragma unroll
    for (int el = 0; el < 4; ++el) hprev[el] = 0.f;

    // ---- prefetch x(t=0) fp32, convert to f16 fragments ----
    float4v xa[8], xb[8];
    {
        const float* xr0 = ins + (size_t)cell_a * HD + kbase;
#pragma unroll
        for (int itl = 0; itl < 8; ++itl) {
            const float4v* px = (const float4v*)(xr0 + itl * 16);
            xa[itl] = px[0];
            xb[itl] = px[1];
        }
    }
    half8 xf[8];
#pragma unroll
    for (int itl = 0; itl < 8; ++itl) {
        half8 v;
#pragma unroll
        for (int e = 0; e < 4; ++e) { v[e] = (f16)xa[itl][e]; v[4 + e] = (f16)xb[itl][e]; }
        xf[itl] = v;
    }

    for (int t = 0; t < T_STEPS; ++t) {
        const f16* hr_ = (t & 1) ? hb1 : hb0;
        f16*       hw_ = (f16*)((t & 1) ? hb0 : hb1);

        // ---- 1. x-part MFMAs (independent of h -> runs in the wait window) ----
        floatx16 ar, az, anx, anh;
#pragma unroll
        for (int i = 0; i < 16; ++i) { ar[i] = 0.f; az[i] = 0.f; anx[i] = 0.f; anh[i] = 0.f; }
#pragma unroll
        for (int itl = 0; itl < 8; ++itl) {
            ar  = __builtin_amdgcn_mfma_f32_32x32x16_f16(xf[itl], bw[0][itl], ar,  0, 0, 0);
            az  = __builtin_amdgcn_mfma_f32_32x32x16_f16(xf[itl], bw[1][itl], az,  0, 0, 0);
            anx = __builtin_amdgcn_mfma_f32_32x32x16_f16(xf[itl], bw[2][itl], anx, 0, 0, 0);
        }

        // ---- 2. prefetch x(t+1) fp32 (in flight across poll + h-load) ----
        {
            int tn = (t + 1 < T_STEPS) ? (t + 1) : t;
            const float* xrn = ins + ((size_t)tn * NCELL + cell_a) * HD + kbase;
#pragma unroll
            for (int itl = 0; itl < 8; ++itl) {
                const float4v* px = (const float4v*)(xrn + itl * 16);
                xa[itl] = px[0];
                xb[itl] = px[1];
            }
        }

        // ---- 3. wait for h(t): all waves poll the 16-flag line directly ----
        // flag[ng']==t means wg ng' finished storing its h(t) slice (h(0)=memset).
        for (;;) {
            int v = __hip_atomic_load(&myflags[lane & 15], __ATOMIC_RELAXED,
                                      __HIP_MEMORY_SCOPE_AGENT);
            if (!__any(v < t)) break;
        }
        asm volatile("" ::: "memory");   // compiler fence: keep h-loads below poll

        // ---- 4. h-loads (sc0sc1 -> MALL, coherent, no cache maintenance) ----
        half8 hf[8];
        {
            const u64* hsrc = (const u64*)(hr_ + (size_t)cell_a * HD + kbase);
#pragma unroll
            for (int itl = 0; itl < 8; ++itl) {
                union { u64 q[2]; half8 v; } u;
                u.q[0] = __hip_atomic_load(hsrc + itl * 4 + 0, __ATOMIC_RELAXED,
                                           __HIP_MEMORY_SCOPE_AGENT);
                u.q[1] = __hip_atomic_load(hsrc + itl * 4 + 1, __ATOMIC_RELAXED,
                                           __HIP_MEMORY_SCOPE_AGENT);
                hf[itl] = u.v;
            }
        }

        // ---- 5. h-part MFMAs ----
#pragma unroll
        for (int itl = 0; itl < 8; ++itl) {
            ar  = __builtin_amdgcn_mfma_f32_32x32x16_f16(hf[itl], bw[3][itl], ar,  0, 0, 0);
            az  = __builtin_amdgcn_mfma_f32_32x32x16_f16(hf[itl], bw[4][itl], az,  0, 0, 0);
            anh = __builtin_amdgcn_mfma_f32_32x32x16_f16(hf[itl], bw[5][itl], anh, 0, 0, 0);
        }

        // ---- 6. every wave dumps all 4 acc quads; convert x(t+1) frags ----
#pragma unroll
        for (int q = 0; q < 4; ++q) {
            float4v v;
            v[0] = ar[4*q]; v[1] = ar[4*q+1]; v[2] = ar[4*q+2]; v[3] = ar[4*q+3];
            *(float4v*)&red[w][0][q][lane][0] = v;
            v[0] = az[4*q]; v[1] = az[4*q+1]; v[2] = az[4*q+2]; v[3] = az[4*q+3];
            *(float4v*)&red[w][1][q][lane][0] = v;
            v[0] = anx[4*q]; v[1] = anx[4*q+1]; v[2] = anx[4*q+2]; v[3] = anx[4*q+3];
            *(float4v*)&red[w][2][q][lane][0] = v;
            v[0] = anh[4*q]; v[1] = anh[4*q+1]; v[2] = anh[4*q+2]; v[3] = anh[4*q+3];
            *(float4v*)&red[w][3][q][lane][0] = v;
        }
        // convert x(t+1) while the LDS writes drain toward the barrier
        {
            half8 xfn[8];
#pragma unroll
            for (int itl = 0; itl < 8; ++itl) {
                half8 v;
#pragma unroll
                for (int e = 0; e < 4; ++e) { v[e] = (f16)xa[itl][e]; v[4 + e] = (f16)xb[itl][e]; }
                xfn[itl] = v;
            }
#pragma unroll
            for (int itl = 0; itl < 8; ++itl) xf[itl] = xfn[itl];
        }
        __syncthreads();

        // ---- 7. wave w reduces quad w (all indices compile-time) ----
        float rr[4], rz[4], rnx[4], rnh[4];
#pragma unroll
        for (int el = 0; el < 4; ++el) { rr[el] = 0.f; rz[el] = 0.f; rnx[el] = 0.f; rnh[el] = 0.f; }
#pragma unroll
        for (int ww = 0; ww < 4; ++ww) {
            float4v v0 = *(const float4v*)&red[ww][0][w][lane][0];
            float4v v1 = *(const float4v*)&red[ww][1][w][lane][0];
            float4v v2 = *(const float4v*)&red[ww][2][w][lane][0];
            float4v v3 = *(const float4v*)&red[ww][3][w][lane][0];
#pragma unroll
            for (int el = 0; el < 4; ++el) {
                rr[el]  += v0[el];
                rz[el]  += v1[el];
                rnx[el] += v2[el];
                rnh[el] += v3[el];
            }
        }

        // ---- 8. elementwise GRU update, 8 rows x 32 cols per wave ----
#pragma unroll
        for (int el = 0; el < 4; ++el) {
            int cell = mg * 32 + row0 + el;
            float var = rr[el]  + bir;
            float vaz = rz[el]  + biz;
            float vnx = rnx[el] + bin;
            float vnh = rnh[el] + bhv;
            float r = 1.0f / (1.0f + __expf(-var));
            float z = 1.0f / (1.0f + __expf(-vaz));
            float hp = hprev[el];                     // register carry
            float narg = vnx + r * vnh;
            narg = fminf(fmaxf(narg, -30.f), 30.f);   // avoid inf/inf in tanh
            float ex = __expf(2.f * narg);
            float n  = (ex - 1.f) / (ex + 1.f);
            float nh = (1.f - z) * n + z * hp;
            out[((size_t)t * NCELL + cell) * HD + col0] = nh;   // pre-reset output
            int rs = resets[t * NCELL + cell];
            float carry = rs ? 0.f : nh;
            hprev[el] = carry;
            union { unsigned short s; f16 h; } cv; cv.h = (f16)carry;
            __hip_atomic_store((unsigned short*)&hw_[(size_t)cell * HD + col0],
                               cv.s, __ATOMIC_RELAXED, __HIP_MEMORY_SCOPE_AGENT);
        }

        // ---- 9. publish: drain stores (barrier implies vmcnt(0)), set flag ----
        __syncthreads();
        if (tid == 0) {
            __hip_atomic_store(&myflags[ng], t + 1, __ATOMIC_RELAXED,
                               __HIP_MEMORY_SCOPE_AGENT);
        }
        // no trailing barrier: next-iteration poll gates each wave individually.
        // LDS reuse is safe: a wave passes the t+1 poll only after its own wg's
        // flag is set, which happens after all waves finished reading red (sync).
    }
}

extern "C" void kernel_launch(void* const* d_in, const int* in_sizes, int n_in,
                              void* d_out, int out_size, void* d_ws, size_t ws_size,
                              hipStream_t stream) {
    const float* ins    = (const float*)d_in[0];
    const int*   resets = (const int*)  d_in[1];
    const float* Wi     = (const float*)d_in[2];
    const float* bi     = (const float*)d_in[3];
    const float* Wh     = (const float*)d_in[4];
    const float* bhn    = (const float*)d_in[5];
    float* out = (float*)d_out;

    char* ws = (char*)d_ws;
    f16* packs = (f16*)ws;
    f16* hbuf  = (f16*)(ws + HBUF_OFF);
    int* flags = (int*)(ws + CNT_OFF);

    // zero h ping-pong buffers + flags (ws re-poisoned to 0xAA each call)
    hipMemsetAsync(ws + HBUF_OFF, 0, (size_t)2 * HBUF_ELEMS * 2 + 4096, stream);

    pack_weights<<<(PACKS_ELEMS + 255) / 256, 256, 0, stream>>>(Wi, Wh, packs);
    gru_scan<<<256, 256, 0, stream>>>(ins, resets, bi, bhn, packs, hbuf, flags, out);
}

// Round 3
// 1707.953 us; speedup vs baseline: 6.2078x; 1.1653x over previous
//
#include <hip/hip_runtime.h>
#include <hip/hip_fp16.h>

// ============================================================================
// GRU scan, T=256, cells=B*A=512, H=512.
//   x_gates = ins @ Wi + bi  (fused, per step)
//   hg      = h   @ Wh
//   r=sig(xr+hr), z=sig(xz+hz), n=tanh(xn + r*(hn+bhn))
//   new_h=(1-z)n+z*h ; carry = reset ? 0 : new_h ; ys[t]=new_h
//
// Decomposition: 16 independent "mg" pipelines of 32 cells each. Each pipeline
// = 16 workgroups (ng = 32-column slice of H).
//
// R3: XCD-local exchange through the per-XCD L2 (coherent for all CUs on one
// XCD; vector L1 is write-through, only the reader's L1 can be stale).
//  * Placement is DISCOVERED, not assumed: each wg reads its physical XCD via
//    s_getreg(HW_REG_XCC_ID) and claims slot=atomicAdd(&xcd_cnt[xcc],1)
//    (device scope, one-time). LDS padded to ~86KB so only 1 wg fits per CU:
//    256 wgs <-> 256 CUs bijectively => exactly 32 wgs per XCD (8 XCDs x 32
//    CUs, capacity argument -- no dispatch-order assumption). slot&15 -> ng,
//    xcc*2+(slot>>4) -> mg. All 16 wgs of an mg share one XCD by construction.
//  * h-stores + flag-store: plain stores (write-through to XCD L2; vmcnt(0)
//    drained by __syncthreads before the flag store, so flag observed =>
//    h-data in L2).
//  * flag-poll + h-loads: inline-asm loads with sc0 (old glc: bypass own L1,
//    served from the shared XCD L2, ~200cy RT vs ~2-4k cy MALL RT) +
//    s_waitcnt vmcnt(0) + sched_barrier(0) (MFMA hoist hazard, rule #18).
//  * R1/R2 lessons kept: NO __threadfence (buffer_wbl2/inv = 4x), flag
//    barrier not atomicAdd, tail parallelized across 4 waves, x-MFMAs +
//    x(t+1) prefetch inside the wait window, per-wave hprev register carry.
//
// Per wg: 4 waves = 4 k-quarters (K=128 each). Weights (6 streams: Wi/Wh x
// r/z/n, f16) live in 192 VGPRs/lane for the whole kernel. A-fragments load
// direct global->VGPR in MFMA A-layout. LDS only for 4-way k-reduction.
// mfma_f32_32x32x16_f16: A lane l: m=l&31, k=8*(l>>5)+j ; B: n=l&31, same k ;
// C: col=l&31, row=(reg&3)+8*(reg>>2)+4*(l>>5).
// ============================================================================

#define T_STEPS 256
#define NCELL   512
#define HD      512
#define G3      1536

typedef _Float16 f16;
typedef _Float16 half8   __attribute__((ext_vector_type(8)));
typedef float    floatx16 __attribute__((ext_vector_type(16)));
typedef float    float4v  __attribute__((ext_vector_type(4)));
typedef unsigned long long u64;

// ws layout (bytes):
//   [0, 3145728)            weight packs f16: [ng(16)][s(6)][it(32)][lane(64)][j(8)]
//   [3145728, 4194304)      h ping-pong: 2 x 512x512 f16
//   [4194304, 4198400)      sync: flags int[16 mg][32] (2048B) + xcd_cnt[8]
#define PACKS_ELEMS (16 * 6 * 32 * 64 * 8)
#define HBUF_OFF    (PACKS_ELEMS * 2)
#define HBUF_ELEMS  (NCELL * HD)
#define CNT_OFF     (HBUF_OFF + 2 * HBUF_ELEMS * 2)

__global__ void pack_weights(const float* __restrict__ Wi,
                             const float* __restrict__ Wh,
                             f16* __restrict__ packs) {
    int idx = blockIdx.x * blockDim.x + threadIdx.x;
    if (idx >= PACKS_ELEMS) return;
    int j  = idx & 7;
    int l  = (idx >> 3) & 63;
    int it = (idx >> 9) & 31;
    int s  = (idx >> 14) % 6;
    int ng = idx / (6 << 14);
    int k    = it * 16 + (l >> 5) * 8 + j;                 // MFMA B k-index
    int gcol = (s % 3) * 512 + ng * 32 + (l & 31);         // gate column
    const float* W = (s < 3) ? Wi : Wh;
    packs[idx] = (f16)W[(size_t)k * G3 + gcol];
}

__launch_bounds__(256, 1)
__global__ void gru_scan(const float* __restrict__ ins,
                         const int*   __restrict__ resets,
                         const float* __restrict__ bi,
                         const float* __restrict__ bhn,
                         const f16*   __restrict__ packs,
                         f16*         __restrict__ hbuf,
                         int*         __restrict__ sync,
                         float*       __restrict__ out) {
    __shared__ float red[4][4][4][64][4];   // 64 KB: [wave][acc][quad][lane][4]
    __shared__ int   lds_pad[5120];         // +20 KB => 86 KB total: forces 1 wg/CU
    __shared__ int   slot_sh;

    const int tid  = threadIdx.x;
    const int lane = tid & 63;
    const int w    = tid >> 6;              // wave = k-quarter
    const int lm   = lane & 31;
    const int lh   = lane >> 5;

    // ---- discover physical XCD; claim a slot among this XCD's 32 wgs ----
    int xcc;
    asm volatile("s_getreg_b32 %0, hwreg(HW_REG_XCC_ID, 0, 32)" : "=s"(xcc));
    xcc &= 7;
    if (tid == 0)
        slot_sh = atomicAdd(&sync[512 + xcc], 1);   // device-scope, one-time
    __syncthreads();
    const int slot = slot_sh;
    if (slot == 0x7fffffff) lds_pad[tid] = tid;     // keep pad alive (never true)
    const int ng = slot & 15;               // 32-column slice of H
    const int mg = xcc * 2 + ((slot >> 4) & 1);   // cell-group; XCD-local by constr.

    // ---- persistent B fragments: 6 streams x 8 k-iters, 192 VGPRs/lane ----
    half8 bw[6][8];
    {
        const half8* p = (const half8*)packs;
#pragma unroll
        for (int s = 0; s < 6; ++s)
#pragma unroll
            for (int itl = 0; itl < 8; ++itl)
                bw[s][itl] = p[((ng * 6 + s) * 32 + (w * 8 + itl)) * 64 + lane];
    }

    // biases (all waves do elementwise)
    const int col0 = ng * 32 + lm;
    const float bir = bi[col0], biz = bi[512 + col0], bin = bi[1024 + col0];
    const float bhv = bhn[col0];

    const int cell_a = mg * 32 + lm;          // A-fragment row (cell)
    const int kbase  = w * 128 + lh * 8;      // A-fragment k base for this lane
    const int row0   = 8 * w + 4 * lh;        // first output row of this wave's quad
    const f16* hb0 = hbuf;
    const f16* hb1 = hbuf + HBUF_ELEMS;
    int* myflags = sync + mg * 32;            // one 128B line per mg
    const int* fladdr = &myflags[lane & 15];

    // per-wave register carry of h for this wave's 8 rows x 32 cols (quad w).
    float hprev[4];
#pragma unroll
    for (int el = 0; el < 4; ++el) hprev[el] = 0.f;

    // ---- prefetch x(t=0) fp32, convert to f16 fragments ----
    float4v xa[8], xb[8];
    {
        const float* xr0 = ins + (size_t)cell_a * HD + kbase;
#pragma unroll
        for (int itl = 0; itl < 8; ++itl) {
            const float4v* px = (const float4v*)(xr0 + itl * 16);
            xa[itl] = px[0];
            xb[itl] = px[1];
        }
    }
    half8 xf[8];
#pragma unroll
    for (int itl = 0; itl < 8; ++itl) {
        half8 v;
#pragma unroll
        for (int e = 0; e < 4; ++e) { v[e] = (f16)xa[itl][e]; v[4 + e] = (f16)xb[itl][e]; }
        xf[itl] = v;
    }

    for (int t = 0; t < T_STEPS; ++t) {
        const f16* hr_ = (t & 1) ? hb1 : hb0;
        f16*       hw_ = (f16*)((t & 1) ? hb0 : hb1);

        // ---- 1. x-part MFMAs (independent of h -> runs in the wait window) ----
        floatx16 ar, az, anx, anh;
#pragma unroll
        for (int i = 0; i < 16; ++i) { ar[i] = 0.f; az[i] = 0.f; anx[i] = 0.f; anh[i] = 0.f; }
#pragma unroll
        for (int itl = 0; itl < 8; ++itl) {
            ar  = __builtin_amdgcn_mfma_f32_32x32x16_f16(xf[itl], bw[0][itl], ar,  0, 0, 0);
            az  = __builtin_amdgcn_mfma_f32_32x32x16_f16(xf[itl], bw[1][itl], az,  0, 0, 0);
            anx = __builtin_amdgcn_mfma_f32_32x32x16_f16(xf[itl], bw[2][itl], anx, 0, 0, 0);
        }

        // ---- 2. prefetch x(t+1) fp32 (in flight across poll + h-load) ----
        {
            int tn = (t + 1 < T_STEPS) ? (t + 1) : t;
            const float* xrn = ins + ((size_t)tn * NCELL + cell_a) * HD + kbase;
#pragma unroll
            for (int itl = 0; itl < 8; ++itl) {
                const float4v* px = (const float4v*)(xrn + itl * 16);
                xa[itl] = px[0];
                xb[itl] = px[1];
            }
        }

        // ---- 3. wait for h(t): all waves poll the flag line via sc0 loads ----
        // (sc0 = bypass own L1, read the shared XCD L2 where producers' plain
        //  stores land; flag==t+1 => producer's h-stores already acked in L2.)
        for (;;) {
            int v;
            asm volatile("global_load_dword %0, %1, off sc0\n\t"
                         "s_waitcnt vmcnt(0)"
                         : "=v"(v) : "v"(fladdr) : "memory");
            if (!__any(v < t)) break;
        }

        // ---- 4. h-loads: sc0 (L1-bypass, XCD-L2 hit) ----
        half8 hf[8];
        {
            const f16* hbase = hr_ + (size_t)cell_a * HD + kbase;
#pragma unroll
            for (int itl = 0; itl < 8; ++itl) {
                asm volatile("global_load_dwordx4 %0, %1, off sc0"
                             : "=v"(hf[itl]) : "v"(hbase + itl * 16) : "memory");
            }
            asm volatile("s_waitcnt vmcnt(0)" ::: "memory");
            __builtin_amdgcn_sched_barrier(0);   // keep MFMAs below the wait
        }

        // ---- 5. h-part MFMAs ----
#pragma unroll
        for (int itl = 0; itl < 8; ++itl) {
            ar  = __builtin_amdgcn_mfma_f32_32x32x16_f16(hf[itl], bw[3][itl], ar,  0, 0, 0);
            az  = __builtin_amdgcn_mfma_f32_32x32x16_f16(hf[itl], bw[4][itl], az,  0, 0, 0);
            anh = __builtin_amdgcn_mfma_f32_32x32x16_f16(hf[itl], bw[5][itl], anh, 0, 0, 0);
        }

        // ---- 6. every wave dumps all 4 acc quads; convert x(t+1) frags ----
#pragma unroll
        for (int q = 0; q < 4; ++q) {
            float4v v;
            v[0] = ar[4*q]; v[1] = ar[4*q+1]; v[2] = ar[4*q+2]; v[3] = ar[4*q+3];
            *(float4v*)&red[w][0][q][lane][0] = v;
            v[0] = az[4*q]; v[1] = az[4*q+1]; v[2] = az[4*q+2]; v[3] = az[4*q+3];
            *(float4v*)&red[w][1][q][lane][0] = v;
            v[0] = anx[4*q]; v[1] = anx[4*q+1]; v[2] = anx[4*q+2]; v[3] = anx[4*q+3];
            *(float4v*)&red[w][2][q][lane][0] = v;
            v[0] = anh[4*q]; v[1] = anh[4*q+1]; v[2] = anh[4*q+2]; v[3] = anh[4*q+3];
            *(float4v*)&red[w][3][q][lane][0] = v;
        }
        // convert x(t+1) while the LDS writes drain toward the barrier
        {
            half8 xfn[8];
#pragma unroll
            for (int itl = 0; itl < 8; ++itl) {
                half8 v;
#pragma unroll
                for (int e = 0; e < 4; ++e) { v[e] = (f16)xa[itl][e]; v[4 + e] = (f16)xb[itl][e]; }
                xfn[itl] = v;
            }
#pragma unroll
            for (int itl = 0; itl < 8; ++itl) xf[itl] = xfn[itl];
        }
        __syncthreads();

        // ---- 7. wave w reduces quad w (all indices compile-time) ----
        float rr[4], rz[4], rnx[4], rnh[4];
#pragma unroll
        for (int el = 0; el < 4; ++el) { rr[el] = 0.f; rz[el] = 0.f; rnx[el] = 0.f; rnh[el] = 0.f; }
#pragma unroll
        for (int ww = 0; ww < 4; ++ww) {
            float4v v0 = *(const float4v*)&red[ww][0][w][lane][0];
            float4v v1 = *(const float4v*)&red[ww][1][w][lane][0];
            float4v v2 = *(const float4v*)&red[ww][2][w][lane][0];
            float4v v3 = *(const float4v*)&red[ww][3][w][lane][0];
#pragma unroll
            for (int el = 0; el < 4; ++el) {
                rr[el]  += v0[el];
                rz[el]  += v1[el];
                rnx[el] += v2[el];
                rnh[el] += v3[el];
            }
        }

        // ---- 8. elementwise GRU update, 8 rows x 32 cols per wave ----
#pragma unroll
        for (int el = 0; el < 4; ++el) {
            int cell = mg * 32 + row0 + el;
            float var = rr[el]  + bir;
            float vaz = rz[el]  + biz;
            float vnx = rnx[el] + bin;
            float vnh = rnh[el] + bhv;
            float r = 1.0f / (1.0f + __expf(-var));
            float z = 1.0f / (1.0f + __expf(-vaz));
            float hp = hprev[el];                     // register carry
            float narg = vnx + r * vnh;
            narg = fminf(fmaxf(narg, -30.f), 30.f);   // avoid inf/inf in tanh
            float ex = __expf(2.f * narg);
            float n  = (ex - 1.f) / (ex + 1.f);
            float nh = (1.f - z) * n + z * hp;
            out[((size_t)t * NCELL + cell) * HD + col0] = nh;   // pre-reset output
            int rs = resets[t * NCELL + cell];
            float carry = rs ? 0.f : nh;
            hprev[el] = carry;
            hw_[(size_t)cell * HD + col0] = (f16)carry;   // plain store -> XCD L2
        }

        // ---- 9. publish: __syncthreads drains vmcnt(0) (h-stores acked in
        //         L2), then tid0 sets the flag with a plain store ----
        __syncthreads();
        if (tid == 0) {
            __hip_atomic_store(&myflags[ng], t + 1, __ATOMIC_RELAXED,
                               __HIP_MEMORY_SCOPE_WORKGROUP);  // plain global_store
        }
        // no trailing barrier: next-iteration poll gates each wave individually.
        // LDS reuse safe: a wave passes poll(t+1) only after its own wg's flag
        // is set, which is after all its waves passed the step-t barrier.
    }
}

extern "C" void kernel_launch(void* const* d_in, const int* in_sizes, int n_in,
                              void* d_out, int out_size, void* d_ws, size_t ws_size,
                              hipStream_t stream) {
    const float* ins    = (const float*)d_in[0];
    const int*   resets = (const int*)  d_in[1];
    const float* Wi     = (const float*)d_in[2];
    const float* bi     = (const float*)d_in[3];
    const float* Wh     = (const float*)d_in[4];
    const float* bhn    = (const float*)d_in[5];
    float* out = (float*)d_out;

    char* ws = (char*)d_ws;
    f16* packs = (f16*)ws;
    f16* hbuf  = (f16*)(ws + HBUF_OFF);
    int* syncp = (int*)(ws + CNT_OFF);

    // zero h ping-pong buffers + sync region (ws re-poisoned to 0xAA each call)
    hipMemsetAsync(ws + HBUF_OFF, 0, (size_t)2 * HBUF_ELEMS * 2 + 4096, stream);

    pack_weights<<<(PACKS_ELEMS + 255) / 256, 256, 0, stream>>>(Wi, Wh, packs);
    gru_scan<<<256, 256, 0, stream>>>(ins, resets, bi, bhn, packs, hbuf, syncp, out);
}